// Round 2
// baseline (491.280 us; speedup 1.0000x reference)
//
#include <hip/hip_runtime.h>
#include <stdint.h>

typedef unsigned short u16;
typedef __attribute__((ext_vector_type(8))) short short8;
typedef __attribute__((ext_vector_type(4))) float f32x4;
typedef __attribute__((ext_vector_type(4))) unsigned short u16x4;

#define DEV __device__ __forceinline__

DEV u16 f2bf(float f) {
  union { float f; unsigned u; } v; v.f = f;
  unsigned r = v.u + 0x7fffu + ((v.u >> 16) & 1u);
  return (u16)(r >> 16);
}
DEV float bf2f(u16 b) {
  union { unsigned u; float f; } v; v.u = ((unsigned)b) << 16;
  return v.f;
}
DEV void gload_lds16(const void* g, void* l) {
  __builtin_amdgcn_global_load_lds((const __attribute__((address_space(1))) void*)g,
                                   (__attribute__((address_space(3))) void*)l,
                                   16, 0, 0);
}

// ---------------- elementwise f32 -> bf16 (vectorized) ----------------
__global__ void k_conv(const float* __restrict__ in, u16* __restrict__ out, int n4) {
  int i = blockIdx.x * blockDim.x + threadIdx.x;
  if (i >= n4) return;
  const f32x4 v = *(const f32x4*)(in + (size_t)i * 4);
  u16x4 o;
  o[0] = f2bf(v[0]); o[1] = f2bf(v[1]); o[2] = f2bf(v[2]); o[3] = f2bf(v[3]);
  *(u16x4*)(out + (size_t)i * 4) = o;
}

// ---------------- transpose + convert: in f32 [R][C] -> out bf16 [C][R] ----------------
__global__ void k_tconv(const float* __restrict__ in, u16* __restrict__ out, int R, int C) {
  __shared__ float tile[32][33];
  int c0 = blockIdx.x * 32, r0 = blockIdx.y * 32;
  int tx = threadIdx.x, ty = threadIdx.y;
#pragma unroll
  for (int j = 0; j < 32; j += 8)
    tile[ty + j][tx] = in[(size_t)(r0 + ty + j) * C + (c0 + tx)];
  __syncthreads();
#pragma unroll
  for (int j = 0; j < 32; j += 8)
    out[(size_t)(c0 + ty + j) * R + (r0 + tx)] = f2bf(tile[tx][ty + j]);
}

// ---------------- RoPE: qkv bf16 [4096][6144] -> qh,kh bf16 [b][h][t][128] ----------------
__global__ void k_rope(const u16* __restrict__ qkv, u16* __restrict__ qh, u16* __restrict__ kh) {
  int m = blockIdx.x;                 // 0..4095 (b*2048 + t)
  int t = m & 2047, b = m >> 11;
  int tid = threadIdx.x;              // 256
  int h = blockIdx.y * 4 + (tid >> 6);
  int j = tid & 63;
  float inv = expf((float)j * -0.14391156831212787f);  // 10000^(-j/64)
  float ang = (float)t * inv;
  float s, c;
  sincosf(ang, &s, &c);
  size_t ibase = (size_t)m * 6144 + (size_t)h * 128;
  size_t obase = ((size_t)(b * 16 + h) * 2048 + t) * 128;
  float q1 = bf2f(qkv[ibase + j]),        q2 = bf2f(qkv[ibase + 64 + j]);
  qh[obase + j]      = f2bf(q1 * c - q2 * s);
  qh[obase + 64 + j] = f2bf(q2 * c + q1 * s);
  float k1 = bf2f(qkv[ibase + 2048 + j]), k2 = bf2f(qkv[ibase + 2048 + 64 + j]);
  kh[obase + j]      = f2bf(k1 * c - k2 * s);
  kh[obase + 64 + j] = f2bf(k2 * c + k1 * s);
}

// ---------------- v transpose: qkv v-part [t][h*128+d] -> vt [bh][d][t] ----------------
__global__ void k_vtrans(const u16* __restrict__ qkv, u16* __restrict__ vt) {
  __shared__ u16 tile[32][33];
  int bh = blockIdx.z;
  int b = bh >> 4, h = bh & 15;
  int t0 = blockIdx.x * 32, d0 = blockIdx.y * 32;
  int tx = threadIdx.x, ty = threadIdx.y;
#pragma unroll
  for (int j = 0; j < 32; j += 8)
    tile[ty + j][tx] = qkv[(size_t)(b * 2048 + t0 + ty + j) * 6144 + 4096 + h * 128 + d0 + tx];
  __syncthreads();
#pragma unroll
  for (int j = 0; j < 32; j += 8)
    vt[((size_t)bh * 128 + d0 + ty + j) * 2048 + (t0 + tx)] = tile[tx][ty + j];
}

// ---------------- GEMM TN: C[M][N] = A[M][K] @ Bt[N][K]^T + bias ----------------
// m97 structure: 128x128 tile, BK=64, 4 waves (2x2), global_load_lds w=16.
// Staging map: LDS row = 64 bf16 = 128 B = 8 lanes x 16 B.
//   chunk = wid*4+i covers rows [chunk*8, chunk*8+8); c = chunk*64+lane;
//   row = c>>3, col-block = (c&7)*8.   (Round-1 fix: was c>>2 / c&3 -> OOB garbage.)
template <bool OUT_BF16>
__global__ __launch_bounds__(256) void k_gemm_tn(const u16* __restrict__ A,
                                                 const u16* __restrict__ Bt,
                                                 const float* __restrict__ bias,
                                                 void* __restrict__ Cv,
                                                 int M, int N, int K) {
  __shared__ __align__(16) short lA[128 * 64];
  __shared__ __align__(16) short lB[128 * 64];
  const int tid = threadIdx.x;
  const int wid = tid >> 6, lane = tid & 63;
  const int bm = blockIdx.x * 128, bn = blockIdx.y * 128;
  const int wm = (wid >> 1) * 64, wn = (wid & 1) * 64;
  const int r = lane & 15, kq = lane >> 4;

  f32x4 acc[4][4];
  const f32x4 zero = {0.f, 0.f, 0.f, 0.f};
#pragma unroll
  for (int i = 0; i < 4; ++i)
#pragma unroll
    for (int j = 0; j < 4; ++j) acc[i][j] = zero;

  for (int k0 = 0; k0 < K; k0 += 64) {
#pragma unroll
    for (int i = 0; i < 4; ++i) {
      int c = (wid * 4 + i) * 64 + lane;
      int row = c >> 3, cb = c & 7;
      gload_lds16(A + (size_t)(bm + row) * K + k0 + cb * 8, (char*)lA + (wid * 4 + i) * 1024);
      gload_lds16(Bt + (size_t)(bn + row) * K + k0 + cb * 8, (char*)lB + (wid * 4 + i) * 1024);
    }
    asm volatile("s_waitcnt vmcnt(0)" ::: "memory");
    __syncthreads();
#pragma unroll
    for (int kk = 0; kk < 2; ++kk) {
      short8 af[4], bfr[4];
#pragma unroll
      for (int mf = 0; mf < 4; ++mf)
        af[mf] = *(const short8*)&lA[(wm + mf * 16 + r) * 64 + kk * 32 + kq * 8];
#pragma unroll
      for (int nf = 0; nf < 4; ++nf)
        bfr[nf] = *(const short8*)&lB[(wn + nf * 16 + r) * 64 + kk * 32 + kq * 8];
#pragma unroll
      for (int mf = 0; mf < 4; ++mf)
#pragma unroll
        for (int nf = 0; nf < 4; ++nf)
          acc[mf][nf] = __builtin_amdgcn_mfma_f32_16x16x32_bf16(af[mf], bfr[nf], acc[mf][nf], 0, 0, 0);
    }
    __syncthreads();
  }
  // epilogue: C/D layout col=lane&15, row=(lane>>4)*4+i
#pragma unroll
  for (int mf = 0; mf < 4; ++mf)
#pragma unroll
    for (int nf = 0; nf < 4; ++nf) {
      int n = bn + wn + nf * 16 + r;
      float bv = bias[n];
#pragma unroll
      for (int i = 0; i < 4; ++i) {
        int m = bm + wm + mf * 16 + kq * 4 + i;
        float val = acc[mf][nf][i] + bv;
        if (OUT_BF16)
          ((u16*)Cv)[(size_t)m * N + n] = f2bf(val);
        else
          ((float*)Cv)[(size_t)m * N + n] = val;
      }
    }
}

// ---------------- causal flash attention ----------------
// block = 256 (4 waves), q-tile 128 rows (32/wave), k-tile 64 keys.
// qh,kh: [bh][t][128] bf16; vt: [bh][128][t] bf16; out: [b*2048+t][h*128+d] bf16
__global__ __launch_bounds__(256) void k_attn(const u16* __restrict__ qh,
                                              const u16* __restrict__ kh,
                                              const u16* __restrict__ vt,
                                              u16* __restrict__ out) {
  __shared__ __align__(16) short lK[64 * 128];
  __shared__ __align__(16) short lV[128 * 64];
  __shared__ __align__(16) short lP[128 * 64];
  const int tid = threadIdx.x, wid = tid >> 6, lane = tid & 63;
  const int qi = 15 - blockIdx.x;   // heavy tiles first
  const int h = blockIdx.y, b = blockIdx.z;
  const int q0 = qi * 128;
  const size_t bh = (size_t)b * 16 + h;
  const u16* qb = qh + bh * 2048 * 128;
  const u16* kb = kh + bh * 2048 * 128;
  const u16* vb = vt + bh * 128 * 2048;
  const int r = lane & 15, kq = lane >> 4;
  const int wrow = wid * 32;
  const float scale = 0.08838834764831845f;  // 1/sqrt(128)

  // Q fragments resident: qa[mf][kk]
  short8 qa[2][4];
#pragma unroll
  for (int mf = 0; mf < 2; ++mf)
#pragma unroll
    for (int kk = 0; kk < 4; ++kk)
      qa[mf][kk] = *(const short8*)(qb + (size_t)(q0 + wrow + mf * 16 + r) * 128 + kk * 32 + kq * 8);

  f32x4 O[2][8];
  const f32x4 zero = {0.f, 0.f, 0.f, 0.f};
#pragma unroll
  for (int mf = 0; mf < 2; ++mf)
#pragma unroll
    for (int nf = 0; nf < 8; ++nf) O[mf][nf] = zero;
  float m_run[2][4], l_run[2][4];
#pragma unroll
  for (int mf = 0; mf < 2; ++mf)
#pragma unroll
    for (int i = 0; i < 4; ++i) { m_run[mf][i] = -1e30f; l_run[mf][i] = 0.f; }

  const int nkt = 2 * (qi + 1);
  for (int kt = 0; kt < nkt; ++kt) {
    const int kt0 = kt * 64;
    // stage K tile [64 keys][128 d] and V^T tile [128 d][64 t]
#pragma unroll
    for (int i = 0; i < 4; ++i) {
      int c = (wid * 4 + i) * 64 + lane;
      gload_lds16(kb + (size_t)(kt0 + (c >> 4)) * 128 + (c & 15) * 8, (char*)lK + (wid * 4 + i) * 1024);
      gload_lds16(vb + (size_t)(c >> 3) * 2048 + kt0 + (c & 7) * 8, (char*)lV + (wid * 4 + i) * 1024);
    }
    asm volatile("s_waitcnt vmcnt(0)" ::: "memory");
    __syncthreads();

    // S = Q @ K^T  (per wave: 32 q-rows x 64 keys)
    f32x4 S[2][4];
#pragma unroll
    for (int mf = 0; mf < 2; ++mf)
#pragma unroll
      for (int nf = 0; nf < 4; ++nf) S[mf][nf] = zero;
#pragma unroll
    for (int kk = 0; kk < 4; ++kk) {
      short8 kf[4];
#pragma unroll
      for (int nf = 0; nf < 4; ++nf)
        kf[nf] = *(const short8*)&lK[(nf * 16 + r) * 128 + kk * 32 + kq * 8];
#pragma unroll
      for (int mf = 0; mf < 2; ++mf)
#pragma unroll
        for (int nf = 0; nf < 4; ++nf)
          S[mf][nf] = __builtin_amdgcn_mfma_f32_16x16x32_bf16(qa[mf][kk], kf[nf], S[mf][nf], 0, 0, 0);
    }

    // scale + causal mask + row max
    float mnew[2][4];
#pragma unroll
    for (int mf = 0; mf < 2; ++mf)
#pragma unroll
      for (int i = 0; i < 4; ++i) mnew[mf][i] = m_run[mf][i];
#pragma unroll
    for (int mf = 0; mf < 2; ++mf)
#pragma unroll
      for (int nf = 0; nf < 4; ++nf)
#pragma unroll
        for (int i = 0; i < 4; ++i) {
          float s = S[mf][nf][i] * scale;
          int qg = q0 + wrow + mf * 16 + kq * 4 + i;
          int kg = kt0 + nf * 16 + r;
          if (kg > qg) s = -1e30f;
          S[mf][nf][i] = s;
          mnew[mf][i] = fmaxf(mnew[mf][i], s);
        }
#pragma unroll
    for (int mf = 0; mf < 2; ++mf)
#pragma unroll
      for (int i = 0; i < 4; ++i) {
        float v = mnew[mf][i];
        v = fmaxf(v, __shfl_xor(v, 1));
        v = fmaxf(v, __shfl_xor(v, 2));
        v = fmaxf(v, __shfl_xor(v, 4));
        v = fmaxf(v, __shfl_xor(v, 8));
        mnew[mf][i] = v;
      }
    // rescale running state + O
    float rs[2][4];
#pragma unroll
    for (int mf = 0; mf < 2; ++mf)
#pragma unroll
      for (int i = 0; i < 4; ++i) {
        float resc = __expf(m_run[mf][i] - mnew[mf][i]);
        l_run[mf][i] *= resc;
        m_run[mf][i] = mnew[mf][i];
        rs[mf][i] = resc;
      }
#pragma unroll
    for (int mf = 0; mf < 2; ++mf)
#pragma unroll
      for (int nf = 0; nf < 8; ++nf)
#pragma unroll
        for (int i = 0; i < 4; ++i) O[mf][nf][i] *= rs[mf][i];

    // P = exp(S - m), write bf16 to LDS, accumulate row sums
#pragma unroll
    for (int mf = 0; mf < 2; ++mf) {
      float lsum[4] = {0.f, 0.f, 0.f, 0.f};
#pragma unroll
      for (int nf = 0; nf < 4; ++nf)
#pragma unroll
        for (int i = 0; i < 4; ++i) {
          float p = __expf(S[mf][nf][i] - m_run[mf][i]);
          lsum[i] += p;
          lP[(wrow + mf * 16 + kq * 4 + i) * 64 + nf * 16 + r] = (short)f2bf(p);
        }
#pragma unroll
      for (int i = 0; i < 4; ++i) {
        float v = lsum[i];
        v += __shfl_xor(v, 1);
        v += __shfl_xor(v, 2);
        v += __shfl_xor(v, 4);
        v += __shfl_xor(v, 8);
        l_run[mf][i] += v;
      }
    }
    __syncthreads();  // lP visible (also orders intra-wave write->read)

    // O += P @ V^T
#pragma unroll
    for (int kk = 0; kk < 2; ++kk) {
      short8 pa[2];
#pragma unroll
      for (int mf = 0; mf < 2; ++mf)
        pa[mf] = *(const short8*)&lP[(wrow + mf * 16 + r) * 64 + kk * 32 + kq * 8];
#pragma unroll
      for (int nf = 0; nf < 8; ++nf) {
        short8 vf = *(const short8*)&lV[(nf * 16 + r) * 64 + kk * 32 + kq * 8];
#pragma unroll
        for (int mf = 0; mf < 2; ++mf)
          O[mf][nf] = __builtin_amdgcn_mfma_f32_16x16x32_bf16(pa[mf], vf, O[mf][nf], 0, 0, 0);
      }
    }
    __syncthreads();  // all reads done before next tile's staging
  }

  // finalize: out[q][h*128+d] = O / l
#pragma unroll
  for (int mf = 0; mf < 2; ++mf) {
    float inv[4];
#pragma unroll
    for (int i = 0; i < 4; ++i) inv[i] = 1.f / l_run[mf][i];
#pragma unroll
    for (int nf = 0; nf < 8; ++nf)
#pragma unroll
      for (int i = 0; i < 4; ++i) {
        int qg = q0 + wrow + mf * 16 + kq * 4 + i;
        out[(size_t)(b * 2048 + qg) * 2048 + h * 128 + nf * 16 + r] = f2bf(O[mf][nf][i] * inv[i]);
      }
  }
}

extern "C" void kernel_launch(void* const* d_in, const int* in_sizes, int n_in,
                              void* d_out, int out_size, void* d_ws, size_t ws_size,
                              hipStream_t stream) {
  const float* x      = (const float*)d_in[0];
  const float* W_attn = (const float*)d_in[1];
  const float* b_attn = (const float*)d_in[2];
  const float* W_proj = (const float*)d_in[3];
  const float* b_proj = (const float*)d_in[4];
  float* y = (float*)d_out;

  // workspace carve-up (bf16 buffers), total 160 MB
  u16* xb     = (u16*)d_ws;                      // [4096][2048]
  u16* wqkvT  = xb     + (size_t)4096 * 2048;    // [6144][2048]
  u16* wprojT = wqkvT  + (size_t)6144 * 2048;    // [2048][2048]
  u16* qkv    = wprojT + (size_t)2048 * 2048;    // [4096][6144]
  u16* qh     = qkv    + (size_t)4096 * 6144;    // [32][2048][128]
  u16* kh     = qh     + (size_t)4096 * 2048;
  u16* vt     = kh     + (size_t)4096 * 2048;    // [32][128][2048]
  u16* attout = vt     + (size_t)4096 * 2048;    // [4096][2048]
  if (ws_size < (size_t)83886080 * 2) return;    // need 160 MB

  k_conv<<<8192, 256, 0, stream>>>(x, xb, 2097152);
  k_tconv<<<dim3(192, 64), dim3(32, 8), 0, stream>>>(W_attn, wqkvT, 2048, 6144);
  k_tconv<<<dim3(64, 64), dim3(32, 8), 0, stream>>>(W_proj, wprojT, 2048, 2048);
  k_gemm_tn<true><<<dim3(32, 48), 256, 0, stream>>>(xb, wqkvT, b_attn, qkv, 4096, 6144, 2048);
  k_rope<<<dim3(4096, 4), 256, 0, stream>>>(qkv, qh, kh);
  k_vtrans<<<dim3(64, 4, 32), dim3(32, 8), 0, stream>>>(qkv, vt);
  k_attn<<<dim3(16, 16, 2), 256, 0, stream>>>(qh, kh, vt, attout);
  k_gemm_tn<false><<<dim3(32, 16), 256, 0, stream>>>(attout, wprojT, b_proj, y, 4096, 2048, 2048);
}

// Round 3
// 348.341 us; speedup vs baseline: 1.4103x; 1.4103x over previous
//
#include <hip/hip_runtime.h>
#include <stdint.h>

typedef unsigned short u16;
typedef __attribute__((ext_vector_type(8))) short short8;
typedef __attribute__((ext_vector_type(4))) float f32x4;
typedef __attribute__((ext_vector_type(4))) unsigned short u16x4;

#define DEV __device__ __forceinline__

DEV u16 f2bf(float f) {
  union { float f; unsigned u; } v; v.f = f;
  unsigned r = v.u + 0x7fffu + ((v.u >> 16) & 1u);
  return (u16)(r >> 16);
}
DEV float bf2f(u16 b) {
  union { unsigned u; float f; } v; v.u = ((unsigned)b) << 16;
  return v.f;
}
DEV void gload_lds16(const void* g, void* l) {
  __builtin_amdgcn_global_load_lds((const __attribute__((address_space(1))) void*)g,
                                   (__attribute__((address_space(3))) void*)l,
                                   16, 0, 0);
}
// raw barrier: no compiler-inserted vmcnt(0) drain (unlike __syncthreads)
DEV void block_barrier() {
  asm volatile("" ::: "memory");
  __builtin_amdgcn_s_barrier();
  asm volatile("" ::: "memory");
}

// ---------------- elementwise f32 -> bf16 (vectorized) ----------------
__global__ void k_conv(const float* __restrict__ in, u16* __restrict__ out, int n4) {
  int i = blockIdx.x * blockDim.x + threadIdx.x;
  if (i >= n4) return;
  const f32x4 v = *(const f32x4*)(in + (size_t)i * 4);
  u16x4 o;
  o[0] = f2bf(v[0]); o[1] = f2bf(v[1]); o[2] = f2bf(v[2]); o[3] = f2bf(v[3]);
  *(u16x4*)(out + (size_t)i * 4) = o;
}

// ---------------- transpose + convert: in f32 [R][C] -> out bf16 [C][R] ----------------
__global__ void k_tconv(const float* __restrict__ in, u16* __restrict__ out, int R, int C) {
  __shared__ float tile[32][33];
  int c0 = blockIdx.x * 32, r0 = blockIdx.y * 32;
  int tx = threadIdx.x, ty = threadIdx.y;
#pragma unroll
  for (int j = 0; j < 32; j += 8)
    tile[ty + j][tx] = in[(size_t)(r0 + ty + j) * C + (c0 + tx)];
  __syncthreads();
#pragma unroll
  for (int j = 0; j < 32; j += 8)
    out[(size_t)(c0 + ty + j) * R + (r0 + tx)] = f2bf(tile[tx][ty + j]);
}

// ---------------- RoPE: qkv bf16 [4096][6144] -> qh,kh bf16 [b][h][t][128] ----------------
__global__ void k_rope(const u16* __restrict__ qkv, u16* __restrict__ qh, u16* __restrict__ kh) {
  int m = blockIdx.x;                 // 0..4095 (b*2048 + t)
  int t = m & 2047, b = m >> 11;
  int tid = threadIdx.x;              // 256
  int h = blockIdx.y * 4 + (tid >> 6);
  int j = tid & 63;
  float inv = expf((float)j * -0.14391156831212787f);  // 10000^(-j/64)
  float ang = (float)t * inv;
  float s, c;
  sincosf(ang, &s, &c);
  size_t ibase = (size_t)m * 6144 + (size_t)h * 128;
  size_t obase = ((size_t)(b * 16 + h) * 2048 + t) * 128;
  float q1 = bf2f(qkv[ibase + j]),        q2 = bf2f(qkv[ibase + 64 + j]);
  qh[obase + j]      = f2bf(q1 * c - q2 * s);
  qh[obase + 64 + j] = f2bf(q2 * c + q1 * s);
  float k1 = bf2f(qkv[ibase + 2048 + j]), k2 = bf2f(qkv[ibase + 2048 + 64 + j]);
  kh[obase + j]      = f2bf(k1 * c - k2 * s);
  kh[obase + 64 + j] = f2bf(k2 * c + k1 * s);
}

// ---------------- v transpose: qkv v-part [t][h*128+d] -> vt [bh][d][t] ----------------
__global__ void k_vtrans(const u16* __restrict__ qkv, u16* __restrict__ vt) {
  __shared__ u16 tile[32][33];
  int bh = blockIdx.z;
  int b = bh >> 4, h = bh & 15;
  int t0 = blockIdx.x * 32, d0 = blockIdx.y * 32;
  int tx = threadIdx.x, ty = threadIdx.y;
#pragma unroll
  for (int j = 0; j < 32; j += 8)
    tile[ty + j][tx] = qkv[(size_t)(b * 2048 + t0 + ty + j) * 6144 + 4096 + h * 128 + d0 + tx];
  __syncthreads();
#pragma unroll
  for (int j = 0; j < 32; j += 8)
    vt[((size_t)bh * 128 + d0 + ty + j) * 2048 + (t0 + tx)] = tile[tx][ty + j];
}

// ---------------- GEMM TN: C[M][N] = A[M][K] @ Bt[N][K]^T + bias ----------------
// m97 structure: 128x128 tile, BK=64, 4 waves (2x2), global_load_lds w=16.
template <bool OUT_BF16>
__global__ __launch_bounds__(256) void k_gemm_tn(const u16* __restrict__ A,
                                                 const u16* __restrict__ Bt,
                                                 const float* __restrict__ bias,
                                                 void* __restrict__ Cv,
                                                 int M, int N, int K) {
  __shared__ __align__(16) short lA[128 * 64];
  __shared__ __align__(16) short lB[128 * 64];
  const int tid = threadIdx.x;
  const int wid = tid >> 6, lane = tid & 63;
  const int bm = blockIdx.x * 128, bn = blockIdx.y * 128;
  const int wm = (wid >> 1) * 64, wn = (wid & 1) * 64;
  const int r = lane & 15, kq = lane >> 4;

  f32x4 acc[4][4];
  const f32x4 zero = {0.f, 0.f, 0.f, 0.f};
#pragma unroll
  for (int i = 0; i < 4; ++i)
#pragma unroll
    for (int j = 0; j < 4; ++j) acc[i][j] = zero;

  for (int k0 = 0; k0 < K; k0 += 64) {
#pragma unroll
    for (int i = 0; i < 4; ++i) {
      int c = (wid * 4 + i) * 64 + lane;
      int row = c >> 3, cb = c & 7;
      gload_lds16(A + (size_t)(bm + row) * K + k0 + cb * 8, (char*)lA + (wid * 4 + i) * 1024);
      gload_lds16(Bt + (size_t)(bn + row) * K + k0 + cb * 8, (char*)lB + (wid * 4 + i) * 1024);
    }
    asm volatile("s_waitcnt vmcnt(0)" ::: "memory");
    __syncthreads();
#pragma unroll
    for (int kk = 0; kk < 2; ++kk) {
      short8 af[4], bfr[4];
#pragma unroll
      for (int mf = 0; mf < 4; ++mf)
        af[mf] = *(const short8*)&lA[(wm + mf * 16 + r) * 64 + kk * 32 + kq * 8];
#pragma unroll
      for (int nf = 0; nf < 4; ++nf)
        bfr[nf] = *(const short8*)&lB[(wn + nf * 16 + r) * 64 + kk * 32 + kq * 8];
#pragma unroll
      for (int mf = 0; mf < 4; ++mf)
#pragma unroll
        for (int nf = 0; nf < 4; ++nf)
          acc[mf][nf] = __builtin_amdgcn_mfma_f32_16x16x32_bf16(af[mf], bfr[nf], acc[mf][nf], 0, 0, 0);
    }
    __syncthreads();
  }
  // epilogue: C/D layout col=lane&15, row=(lane>>4)*4+i
#pragma unroll
  for (int mf = 0; mf < 4; ++mf)
#pragma unroll
    for (int nf = 0; nf < 4; ++nf) {
      int n = bn + wn + nf * 16 + r;
      float bv = bias[n];
#pragma unroll
      for (int i = 0; i < 4; ++i) {
        int m = bm + wm + mf * 16 + kq * 4 + i;
        float val = acc[mf][nf][i] + bv;
        if (OUT_BF16)
          ((u16*)Cv)[(size_t)m * N + n] = f2bf(val);
        else
          ((float*)Cv)[(size_t)m * N + n] = val;
      }
    }
}

// ---------------- causal flash attention v2 ----------------
// Balanced pairing: block p handles q-tiles j=p and j=31-p (QBLK=64) -> exactly 33
// k-tiles (KBLK=64) per block. 512 blocks = 2/CU, all co-resident, uniform work.
// Dbuf K/V staging with counted vmcnt(8); XOR-swizzled LDS (T2, rule-21 pattern:
// pre-swizzled global source for gload_lds + swizzled reads).
// qh,kh: [bh][t][128] bf16; vt: [bh][128][t] bf16; out: [b*2048+t][h*128+d] bf16
__global__ __launch_bounds__(256) void k_attn(const u16* __restrict__ qh,
                                              const u16* __restrict__ kh,
                                              const u16* __restrict__ vt,
                                              u16* __restrict__ out) {
  __shared__ __align__(16) short lK[2][64 * 128];   // 32 KB (swizzled rows of 256 B)
  __shared__ __align__(16) short lV[2][128 * 64];   // 32 KB (swizzled rows of 128 B)
  __shared__ __align__(16) short lP[64 * 64];       // 8 KB  (wave-private rows, swizzled)
  const int tid = threadIdx.x, wid = tid >> 6, lane = tid & 63;
  const int p = blockIdx.x, h = blockIdx.y, b = blockIdx.z;
  const size_t bh = (size_t)b * 16 + h;
  const u16* qb = qh + bh * 2048 * 128;
  const u16* kb = kh + bh * 2048 * 128;
  const u16* vb = vt + bh * 128 * 2048;
  const int r = lane & 15, kq = lane >> 4;
  const int r7 = r & 7;
  const int wrow = wid * 16;
  const float scale2 = 0.08838834764831845f * 1.4426950408889634f;  // 1/sqrt(128) * log2(e)

  // per-lane staging source offsets (tile-invariant part); source chunk pre-swizzled
  int koff[4], voff[4];
#pragma unroll
  for (int i = 0; i < 4; ++i) {
    int ci = (wid * 4 + i) * 64 + lane;
    int krow = ci >> 4, kch = ci & 15;          // K tile: 64 rows x 16 chunks(16B)
    koff[i] = krow * 128 + ((kch ^ (krow & 7)) * 8);
    int vrow = ci >> 3, vch = ci & 7;           // V tile: 128 rows x 8 chunks(16B)
    voff[i] = vrow * 2048 + ((vch ^ (vrow & 7)) * 8);
  }

#pragma unroll 1
  for (int seg = 0; seg < 2; ++seg) {
    const int j = seg ? 31 - p : p;
    const int q0 = j * 64;
    const int nkt = j + 1;

    // Q fragments resident (wave's 16 rows)
    short8 qa[4];
#pragma unroll
    for (int kk = 0; kk < 4; ++kk)
      qa[kk] = *(const short8*)(qb + (size_t)(q0 + wrow + r) * 128 + kk * 32 + kq * 8);

    f32x4 O[8];
    const f32x4 zero = {0.f, 0.f, 0.f, 0.f};
#pragma unroll
    for (int nf = 0; nf < 8; ++nf) O[nf] = zero;
    float m_run[4], l_run[4];
#pragma unroll
    for (int i = 0; i < 4; ++i) { m_run[i] = -1e30f; l_run[i] = 0.f; }

    // prologue stage tile 0 -> buf 0
#pragma unroll
    for (int i = 0; i < 4; ++i) {
      gload_lds16(kb + koff[i], (char*)&lK[0][0] + (wid * 4 + i) * 1024);
      gload_lds16(vb + voff[i], (char*)&lV[0][0] + (wid * 4 + i) * 1024);
    }

#pragma unroll 1
    for (int kt = 0; kt < nkt; ++kt) {
      const int cur = kt & 1;
      if (kt + 1 < nkt) {
        const size_t kbase = (size_t)(kt + 1) * 8192, vbase = (size_t)(kt + 1) * 64;
#pragma unroll
        for (int i = 0; i < 4; ++i) {
          gload_lds16(kb + kbase + koff[i], (char*)&lK[cur ^ 1][0] + (wid * 4 + i) * 1024);
          gload_lds16(vb + vbase + voff[i], (char*)&lV[cur ^ 1][0] + (wid * 4 + i) * 1024);
        }
        asm volatile("s_waitcnt vmcnt(8)" ::: "memory");  // current tile landed, next in flight
      } else {
        asm volatile("s_waitcnt vmcnt(0)" ::: "memory");
      }
      block_barrier();

      // S = Q @ K^T (wave: 16 q-rows x 64 keys)
      f32x4 S[4];
#pragma unroll
      for (int nf = 0; nf < 4; ++nf) S[nf] = zero;
#pragma unroll
      for (int kk = 0; kk < 4; ++kk) {
        short8 kf[4];
#pragma unroll
        for (int nf = 0; nf < 4; ++nf)
          kf[nf] = *(const short8*)&lK[cur][(nf * 16 + r) * 128 + ((kk * 4 + kq) ^ r7) * 8];
#pragma unroll
        for (int nf = 0; nf < 4; ++nf)
          S[nf] = __builtin_amdgcn_mfma_f32_16x16x32_bf16(qa[kk], kf[nf], S[nf], 0, 0, 0);
      }

      // scale (exp2 domain) + causal mask (diagonal tile only) + row max
      float mnew[4];
#pragma unroll
      for (int i = 0; i < 4; ++i) mnew[i] = m_run[i];
      if (kt == nkt - 1) {
#pragma unroll
        for (int nf = 0; nf < 4; ++nf)
#pragma unroll
          for (int i = 0; i < 4; ++i) {
            float s = S[nf][i] * scale2;
            int kg = kt * 64 + nf * 16 + r;
            int qg = q0 + wrow + kq * 4 + i;
            s = (kg > qg) ? -1e30f : s;
            S[nf][i] = s;
            mnew[i] = fmaxf(mnew[i], s);
          }
      } else {
#pragma unroll
        for (int nf = 0; nf < 4; ++nf)
#pragma unroll
          for (int i = 0; i < 4; ++i) {
            float s = S[nf][i] * scale2;
            S[nf][i] = s;
            mnew[i] = fmaxf(mnew[i], s);
          }
      }
#pragma unroll
      for (int i = 0; i < 4; ++i) {
        float v = mnew[i];
        v = fmaxf(v, __shfl_xor(v, 1));
        v = fmaxf(v, __shfl_xor(v, 2));
        v = fmaxf(v, __shfl_xor(v, 4));
        v = fmaxf(v, __shfl_xor(v, 8));
        mnew[i] = v;
      }
      float rs[4];
#pragma unroll
      for (int i = 0; i < 4; ++i) {
        rs[i] = exp2f(m_run[i] - mnew[i]);
        l_run[i] *= rs[i];
        m_run[i] = mnew[i];
      }
#pragma unroll
      for (int nf = 0; nf < 8; ++nf)
#pragma unroll
        for (int i = 0; i < 4; ++i) O[nf][i] *= rs[i];

      // P = exp2(S - m) -> bf16 -> lP (wave-private rows, swizzled); row sums
      {
        float lsum[4] = {0.f, 0.f, 0.f, 0.f};
#pragma unroll
        for (int nf = 0; nf < 4; ++nf)
#pragma unroll
          for (int i = 0; i < 4; ++i) {
            float pv = exp2f(S[nf][i] - m_run[i]);
            lsum[i] += pv;
            int row = wrow + kq * 4 + i;
            int cl = (nf * 2 + (r >> 3)) ^ ((kq * 4 + i) & 7);
            lP[row * 64 + cl * 8 + r7] = (short)f2bf(pv);
          }
#pragma unroll
        for (int i = 0; i < 4; ++i) {
          float v = lsum[i];
          v += __shfl_xor(v, 1);
          v += __shfl_xor(v, 2);
          v += __shfl_xor(v, 4);
          v += __shfl_xor(v, 8);
          l_run[i] += v;
        }
      }

      // O += P @ V^T (P rows wave-private; V read-only under barriers)
#pragma unroll
      for (int kk = 0; kk < 2; ++kk) {
        short8 pa = *(const short8*)&lP[(wrow + r) * 64 + ((kk * 4 + kq) ^ r7) * 8];
#pragma unroll
        for (int nf = 0; nf < 8; ++nf) {
          short8 vf = *(const short8*)&lV[cur][(nf * 16 + r) * 64 + ((kk * 4 + kq) ^ r7) * 8];
          O[nf] = __builtin_amdgcn_mfma_f32_16x16x32_bf16(pa, vf, O[nf], 0, 0, 0);
        }
      }
      asm volatile("s_waitcnt lgkmcnt(0)" ::: "memory");
      block_barrier();  // all reads done before next stage overwrites
    }

    // finalize: out[q][h*128+d] = O / l
    float inv[4];
#pragma unroll
    for (int i = 0; i < 4; ++i) inv[i] = 1.f / l_run[i];
#pragma unroll
    for (int nf = 0; nf < 8; ++nf)
#pragma unroll
      for (int i = 0; i < 4; ++i) {
        int qg = q0 + wrow + kq * 4 + i;
        out[(size_t)(b * 2048 + qg) * 2048 + h * 128 + nf * 16 + r] = f2bf(O[nf][i] * inv[i]);
      }
  }
}

extern "C" void kernel_launch(void* const* d_in, const int* in_sizes, int n_in,
                              void* d_out, int out_size, void* d_ws, size_t ws_size,
                              hipStream_t stream) {
  const float* x      = (const float*)d_in[0];
  const float* W_attn = (const float*)d_in[1];
  const float* b_attn = (const float*)d_in[2];
  const float* W_proj = (const float*)d_in[3];
  const float* b_proj = (const float*)d_in[4];
  float* y = (float*)d_out;

  // workspace carve-up (bf16 buffers), total 160 MB
  u16* xb     = (u16*)d_ws;                      // [4096][2048]
  u16* wqkvT  = xb     + (size_t)4096 * 2048;    // [6144][2048]
  u16* wprojT = wqkvT  + (size_t)6144 * 2048;    // [2048][2048]
  u16* qkv    = wprojT + (size_t)2048 * 2048;    // [4096][6144]
  u16* qh     = qkv    + (size_t)4096 * 6144;    // [32][2048][128]
  u16* kh     = qh     + (size_t)4096 * 2048;
  u16* vt     = kh     + (size_t)4096 * 2048;    // [32][128][2048]
  u16* attout = vt     + (size_t)4096 * 2048;    // [4096][2048]
  if (ws_size < (size_t)83886080 * 2) return;    // need 160 MB

  k_conv<<<8192, 256, 0, stream>>>(x, xb, 2097152);
  k_tconv<<<dim3(192, 64), dim3(32, 8), 0, stream>>>(W_attn, wqkvT, 2048, 6144);
  k_tconv<<<dim3(64, 64), dim3(32, 8), 0, stream>>>(W_proj, wprojT, 2048, 2048);
  k_gemm_tn<true><<<dim3(32, 48), 256, 0, stream>>>(xb, wqkvT, b_attn, qkv, 4096, 6144, 2048);
  k_rope<<<dim3(4096, 4), 256, 0, stream>>>(qkv, qh, kh);
  k_vtrans<<<dim3(64, 4, 32), dim3(32, 8), 0, stream>>>(qkv, vt);
  k_attn<<<dim3(16, 16, 2), 256, 0, stream>>>(qh, kh, vt, attout);
  k_gemm_tn<false><<<dim3(32, 16), 256, 0, stream>>>(attout, wprojT, b_proj, y, 4096, 2048, 2048);
}

// Round 4
// 332.436 us; speedup vs baseline: 1.4778x; 1.0478x over previous
//
#include <hip/hip_runtime.h>
#include <stdint.h>

typedef unsigned short u16;
typedef __attribute__((ext_vector_type(8))) short short8;
typedef __attribute__((ext_vector_type(4))) float f32x4;
typedef __attribute__((ext_vector_type(4))) unsigned short u16x4;

#define DEV __device__ __forceinline__

DEV u16 f2bf(float f) {
  union { float f; unsigned u; } v; v.f = f;
  unsigned r = v.u + 0x7fffu + ((v.u >> 16) & 1u);
  return (u16)(r >> 16);
}
DEV float bf2f(u16 b) {
  union { unsigned u; float f; } v; v.u = ((unsigned)b) << 16;
  return v.f;
}
DEV void gload_lds16(const void* g, void* l) {
  __builtin_amdgcn_global_load_lds((const __attribute__((address_space(1))) void*)g,
                                   (__attribute__((address_space(3))) void*)l,
                                   16, 0, 0);
}
// raw barrier: no compiler-inserted vmcnt(0) drain (unlike __syncthreads)
DEV void block_barrier() {
  asm volatile("" ::: "memory");
  __builtin_amdgcn_s_barrier();
  asm volatile("" ::: "memory");
}

// ---------------- elementwise f32 -> bf16 (vectorized) ----------------
__global__ void k_conv(const float* __restrict__ in, u16* __restrict__ out, int n4) {
  int i = blockIdx.x * blockDim.x + threadIdx.x;
  if (i >= n4) return;
  const f32x4 v = *(const f32x4*)(in + (size_t)i * 4);
  u16x4 o;
  o[0] = f2bf(v[0]); o[1] = f2bf(v[1]); o[2] = f2bf(v[2]); o[3] = f2bf(v[3]);
  *(u16x4*)(out + (size_t)i * 4) = o;
}

// ---------------- transpose + convert: in f32 [R][C] -> out bf16 [C][R] ----------------
__global__ void k_tconv(const float* __restrict__ in, u16* __restrict__ out, int R, int C) {
  __shared__ float tile[32][33];
  int c0 = blockIdx.x * 32, r0 = blockIdx.y * 32;
  int tx = threadIdx.x, ty = threadIdx.y;
#pragma unroll
  for (int j = 0; j < 32; j += 8)
    tile[ty + j][tx] = in[(size_t)(r0 + ty + j) * C + (c0 + tx)];
  __syncthreads();
#pragma unroll
  for (int j = 0; j < 32; j += 8)
    out[(size_t)(c0 + ty + j) * R + (r0 + tx)] = f2bf(tile[tx][ty + j]);
}

// ---------------- RoPE: qkv bf16 [4096][6144] -> qh,kh bf16 [b][h][t][128] ----------------
__global__ void k_rope(const u16* __restrict__ qkv, u16* __restrict__ qh, u16* __restrict__ kh) {
  int m = blockIdx.x;                 // 0..4095 (b*2048 + t)
  int t = m & 2047, b = m >> 11;
  int tid = threadIdx.x;              // 256
  int h = blockIdx.y * 4 + (tid >> 6);
  int j = tid & 63;
  float inv = expf((float)j * -0.14391156831212787f);  // 10000^(-j/64)
  float ang = (float)t * inv;
  float s, c;
  sincosf(ang, &s, &c);
  size_t ibase = (size_t)m * 6144 + (size_t)h * 128;
  size_t obase = ((size_t)(b * 16 + h) * 2048 + t) * 128;
  float q1 = bf2f(qkv[ibase + j]),        q2 = bf2f(qkv[ibase + 64 + j]);
  qh[obase + j]      = f2bf(q1 * c - q2 * s);
  qh[obase + 64 + j] = f2bf(q2 * c + q1 * s);
  float k1 = bf2f(qkv[ibase + 2048 + j]), k2 = bf2f(qkv[ibase + 2048 + 64 + j]);
  kh[obase + j]      = f2bf(k1 * c - k2 * s);
  kh[obase + 64 + j] = f2bf(k2 * c + k1 * s);
}

// ---------------- v transpose: qkv v-part [t][h*128+d] -> vt [bh][d][t] ----------------
__global__ void k_vtrans(const u16* __restrict__ qkv, u16* __restrict__ vt) {
  __shared__ u16 tile[32][33];
  int bh = blockIdx.z;
  int b = bh >> 4, h = bh & 15;
  int t0 = blockIdx.x * 32, d0 = blockIdx.y * 32;
  int tx = threadIdx.x, ty = threadIdx.y;
#pragma unroll
  for (int j = 0; j < 32; j += 8)
    tile[ty + j][tx] = qkv[(size_t)(b * 2048 + t0 + ty + j) * 6144 + 4096 + h * 128 + d0 + tx];
  __syncthreads();
#pragma unroll
  for (int j = 0; j < 32; j += 8)
    vt[((size_t)bh * 128 + d0 + ty + j) * 2048 + (t0 + tx)] = tile[tx][ty + j];
}

// ---------------- GEMM TN v2: C[M][N] = A[M][K] @ Bt[N][K]^T + bias ----------------
// 128x256 tile, BK=64, 8 waves (2M x 4N), 96 KB LDS dbuf.
// Deep prefetch: tile t+2 staged right after buffer cur is retired; counted
// vmcnt(6) waits only for tile t+1 (issued one full tile earlier). No vmcnt(0)
// in main loop. T2 read-swizzle chunk^=(row&7) via pre-swizzled global source
// (rule 21: linear LDS dest + inverse-swizzled source + swizzled ds_read).
template <bool OUT_BF16>
__global__ __launch_bounds__(512, 2) void k_gemm2(const u16* __restrict__ A,
                                                  const u16* __restrict__ Bt,
                                                  const float* __restrict__ bias,
                                                  void* __restrict__ Cv,
                                                  int M, int N, int K) {
  __shared__ __align__(16) short lA[2][128 * 64];   // 2 x 16 KB
  __shared__ __align__(16) short lB[2][256 * 64];   // 2 x 32 KB
  const int tid = threadIdx.x;
  const int wid = tid >> 6, lane = tid & 63;
  const int bm = blockIdx.x * 128, bn = blockIdx.y * 256;
  const int wm = (wid >> 2) * 64, wn = (wid & 3) * 64;
  const int r = lane & 15, kq = lane >> 4, r7 = lane & 7;

  // staging maps: tile row = 64 bf16 = 128 B = 8 chunks of 16 B.
  // chunk c = i*512 + wid*64 + lane; row = c>>3, ch = c&7; source pre-swizzled.
  size_t aoff[2]; int albase[2];
#pragma unroll
  for (int i = 0; i < 2; ++i) {
    int c = i * 512 + wid * 64 + lane;
    int row = c >> 3, ch = c & 7;
    aoff[i] = (size_t)(bm + row) * K + (ch ^ (row & 7)) * 8;
    albase[i] = (i * 512 + wid * 64) * 16;   // wave-uniform LDS byte base
  }
  size_t boff[4]; int blbase[4];
#pragma unroll
  for (int i = 0; i < 4; ++i) {
    int c = i * 512 + wid * 64 + lane;
    int row = c >> 3, ch = c & 7;
    boff[i] = (size_t)(bn + row) * K + (ch ^ (row & 7)) * 8;
    blbase[i] = (i * 512 + wid * 64) * 16;
  }

  f32x4 acc[4][4];
  const f32x4 zero = {0.f, 0.f, 0.f, 0.f};
#pragma unroll
  for (int i = 0; i < 4; ++i)
#pragma unroll
    for (int j = 0; j < 4; ++j) acc[i][j] = zero;

  const int nt = K >> 6;

#define STAGE_TILE(k0, buf)                                                     \
  do {                                                                          \
    _Pragma("unroll")                                                           \
    for (int i = 0; i < 2; ++i)                                                 \
      gload_lds16(A + aoff[i] + (k0), (char*)&lA[(buf)][0] + albase[i]);        \
    _Pragma("unroll")                                                           \
    for (int i = 0; i < 4; ++i)                                                 \
      gload_lds16(Bt + boff[i] + (k0), (char*)&lB[(buf)][0] + blbase[i]);       \
  } while (0)

  // prologue: tiles 0 and 1 in flight; wait for tile 0 only.
  STAGE_TILE(0, 0);
  if (nt > 1) {
    STAGE_TILE(64, 1);
    asm volatile("s_waitcnt vmcnt(6)" ::: "memory");
  } else {
    asm volatile("s_waitcnt vmcnt(0)" ::: "memory");
  }
  block_barrier();

#pragma unroll 1
  for (int t = 0; t < nt; ++t) {
    const int cur = t & 1;
    const short* As = &lA[cur][0];
    const short* Bs = &lB[cur][0];
    short8 af[2][4], bfv[2][4];
#pragma unroll
    for (int kk = 0; kk < 2; ++kk) {
#pragma unroll
      for (int mf = 0; mf < 4; ++mf)
        af[kk][mf] = *(const short8*)&As[(wm + mf * 16 + r) * 64 + ((kk * 4 + kq) ^ r7) * 8];
#pragma unroll
      for (int nf = 0; nf < 4; ++nf)
        bfv[kk][nf] = *(const short8*)&Bs[(wn + nf * 16 + r) * 64 + ((kk * 4 + kq) ^ r7) * 8];
    }
    __builtin_amdgcn_s_setprio(1);
#pragma unroll
    for (int kk = 0; kk < 2; ++kk)
#pragma unroll
      for (int mf = 0; mf < 4; ++mf)
#pragma unroll
        for (int nf = 0; nf < 4; ++nf)
          acc[mf][nf] = __builtin_amdgcn_mfma_f32_16x16x32_bf16(af[kk][mf], bfv[kk][nf], acc[mf][nf], 0, 0, 0);
    __builtin_amdgcn_s_setprio(0);

    if (t < nt - 1) {
      block_barrier();                 // all waves done reading buf cur
      if (t + 2 < nt) {
        STAGE_TILE((t + 2) * 64, cur); // reuse cur for tile t+2
        asm volatile("s_waitcnt vmcnt(6)" ::: "memory");  // tile t+1 landed; t+2 in flight
      } else {
        asm volatile("s_waitcnt vmcnt(0)" ::: "memory");  // drain last tile
      }
      block_barrier();                 // collective: tile t+1 resident
    }
  }
#undef STAGE_TILE

  // epilogue: C/D layout col=lane&15, row=(lane>>4)*4+i
#pragma unroll
  for (int mf = 0; mf < 4; ++mf)
#pragma unroll
    for (int nf = 0; nf < 4; ++nf) {
      int n = bn + wn + nf * 16 + r;
      float bv = bias[n];
#pragma unroll
      for (int i = 0; i < 4; ++i) {
        int m = bm + wm + mf * 16 + kq * 4 + i;
        float val = acc[mf][nf][i] + bv;
        if (OUT_BF16)
          ((u16*)Cv)[(size_t)m * N + n] = f2bf(val);
        else
          ((float*)Cv)[(size_t)m * N + n] = val;
      }
    }
}

// ---------------- causal flash attention v2 ----------------
// Balanced pairing: block p handles q-tiles j=p and j=31-p (QBLK=64) -> exactly 33
// k-tiles (KBLK=64) per block. 512 blocks = 2/CU, all co-resident, uniform work.
// Dbuf K/V staging with counted vmcnt(8); XOR-swizzled LDS (T2, rule-21 pattern:
// pre-swizzled global source for gload_lds + swizzled reads).
// qh,kh: [bh][t][128] bf16; vt: [bh][128][t] bf16; out: [b*2048+t][h*128+d] bf16
__global__ __launch_bounds__(256) void k_attn(const u16* __restrict__ qh,
                                              const u16* __restrict__ kh,
                                              const u16* __restrict__ vt,
                                              u16* __restrict__ out) {
  __shared__ __align__(16) short lK[2][64 * 128];   // 32 KB (swizzled rows of 256 B)
  __shared__ __align__(16) short lV[2][128 * 64];   // 32 KB (swizzled rows of 128 B)
  __shared__ __align__(16) short lP[64 * 64];       // 8 KB  (wave-private rows, swizzled)
  const int tid = threadIdx.x, wid = tid >> 6, lane = tid & 63;
  const int p = blockIdx.x, h = blockIdx.y, b = blockIdx.z;
  const size_t bh = (size_t)b * 16 + h;
  const u16* qb = qh + bh * 2048 * 128;
  const u16* kb = kh + bh * 2048 * 128;
  const u16* vb = vt + bh * 128 * 2048;
  const int r = lane & 15, kq = lane >> 4;
  const int r7 = r & 7;
  const int wrow = wid * 16;
  const float scale2 = 0.08838834764831845f * 1.4426950408889634f;  // 1/sqrt(128) * log2(e)

  // per-lane staging source offsets (tile-invariant part); source chunk pre-swizzled
  int koff[4], voff[4];
#pragma unroll
  for (int i = 0; i < 4; ++i) {
    int ci = (wid * 4 + i) * 64 + lane;
    int krow = ci >> 4, kch = ci & 15;          // K tile: 64 rows x 16 chunks(16B)
    koff[i] = krow * 128 + ((kch ^ (krow & 7)) * 8);
    int vrow = ci >> 3, vch = ci & 7;           // V tile: 128 rows x 8 chunks(16B)
    voff[i] = vrow * 2048 + ((vch ^ (vrow & 7)) * 8);
  }

#pragma unroll 1
  for (int seg = 0; seg < 2; ++seg) {
    const int j = seg ? 31 - p : p;
    const int q0 = j * 64;
    const int nkt = j + 1;

    // Q fragments resident (wave's 16 rows)
    short8 qa[4];
#pragma unroll
    for (int kk = 0; kk < 4; ++kk)
      qa[kk] = *(const short8*)(qb + (size_t)(q0 + wrow + r) * 128 + kk * 32 + kq * 8);

    f32x4 O[8];
    const f32x4 zero = {0.f, 0.f, 0.f, 0.f};
#pragma unroll
    for (int nf = 0; nf < 8; ++nf) O[nf] = zero;
    float m_run[4], l_run[4];
#pragma unroll
    for (int i = 0; i < 4; ++i) { m_run[i] = -1e30f; l_run[i] = 0.f; }

    // prologue stage tile 0 -> buf 0
#pragma unroll
    for (int i = 0; i < 4; ++i) {
      gload_lds16(kb + koff[i], (char*)&lK[0][0] + (wid * 4 + i) * 1024);
      gload_lds16(vb + voff[i], (char*)&lV[0][0] + (wid * 4 + i) * 1024);
    }

#pragma unroll 1
    for (int kt = 0; kt < nkt; ++kt) {
      const int cur = kt & 1;
      if (kt + 1 < nkt) {
        const size_t kbase = (size_t)(kt + 1) * 8192, vbase = (size_t)(kt + 1) * 64;
#pragma unroll
        for (int i = 0; i < 4; ++i) {
          gload_lds16(kb + kbase + koff[i], (char*)&lK[cur ^ 1][0] + (wid * 4 + i) * 1024);
          gload_lds16(vb + vbase + voff[i], (char*)&lV[cur ^ 1][0] + (wid * 4 + i) * 1024);
        }
        asm volatile("s_waitcnt vmcnt(8)" ::: "memory");  // current tile landed, next in flight
      } else {
        asm volatile("s_waitcnt vmcnt(0)" ::: "memory");
      }
      block_barrier();

      // S = Q @ K^T (wave: 16 q-rows x 64 keys)
      f32x4 S[4];
#pragma unroll
      for (int nf = 0; nf < 4; ++nf) S[nf] = zero;
#pragma unroll
      for (int kk = 0; kk < 4; ++kk) {
        short8 kf[4];
#pragma unroll
        for (int nf = 0; nf < 4; ++nf)
          kf[nf] = *(const short8*)&lK[cur][(nf * 16 + r) * 128 + ((kk * 4 + kq) ^ r7) * 8];
#pragma unroll
        for (int nf = 0; nf < 4; ++nf)
          S[nf] = __builtin_amdgcn_mfma_f32_16x16x32_bf16(qa[kk], kf[nf], S[nf], 0, 0, 0);
      }

      // scale (exp2 domain) + causal mask (diagonal tile only) + row max
      float mnew[4];
#pragma unroll
      for (int i = 0; i < 4; ++i) mnew[i] = m_run[i];
      if (kt == nkt - 1) {
#pragma unroll
        for (int nf = 0; nf < 4; ++nf)
#pragma unroll
          for (int i = 0; i < 4; ++i) {
            float s = S[nf][i] * scale2;
            int kg = kt * 64 + nf * 16 + r;
            int qg = q0 + wrow + kq * 4 + i;
            s = (kg > qg) ? -1e30f : s;
            S[nf][i] = s;
            mnew[i] = fmaxf(mnew[i], s);
          }
      } else {
#pragma unroll
        for (int nf = 0; nf < 4; ++nf)
#pragma unroll
          for (int i = 0; i < 4; ++i) {
            float s = S[nf][i] * scale2;
            S[nf][i] = s;
            mnew[i] = fmaxf(mnew[i], s);
          }
      }
#pragma unroll
      for (int i = 0; i < 4; ++i) {
        float v = mnew[i];
        v = fmaxf(v, __shfl_xor(v, 1));
        v = fmaxf(v, __shfl_xor(v, 2));
        v = fmaxf(v, __shfl_xor(v, 4));
        v = fmaxf(v, __shfl_xor(v, 8));
        mnew[i] = v;
      }
      float rs[4];
#pragma unroll
      for (int i = 0; i < 4; ++i) {
        rs[i] = exp2f(m_run[i] - mnew[i]);
        l_run[i] *= rs[i];
        m_run[i] = mnew[i];
      }
#pragma unroll
      for (int nf = 0; nf < 8; ++nf)
#pragma unroll
        for (int i = 0; i < 4; ++i) O[nf][i] *= rs[i];

      // P = exp2(S - m) -> bf16 -> lP (wave-private rows, swizzled); row sums
      {
        float lsum[4] = {0.f, 0.f, 0.f, 0.f};
#pragma unroll
        for (int nf = 0; nf < 4; ++nf)
#pragma unroll
          for (int i = 0; i < 4; ++i) {
            float pv = exp2f(S[nf][i] - m_run[i]);
            lsum[i] += pv;
            int row = wrow + kq * 4 + i;
            int cl = (nf * 2 + (r >> 3)) ^ ((kq * 4 + i) & 7);
            lP[row * 64 + cl * 8 + r7] = (short)f2bf(pv);
          }
#pragma unroll
        for (int i = 0; i < 4; ++i) {
          float v = lsum[i];
          v += __shfl_xor(v, 1);
          v += __shfl_xor(v, 2);
          v += __shfl_xor(v, 4);
          v += __shfl_xor(v, 8);
          l_run[i] += v;
        }
      }

      // O += P @ V^T (P rows wave-private; V read-only under barriers)
#pragma unroll
      for (int kk = 0; kk < 2; ++kk) {
        short8 pa = *(const short8*)&lP[(wrow + r) * 64 + ((kk * 4 + kq) ^ r7) * 8];
#pragma unroll
        for (int nf = 0; nf < 8; ++nf) {
          short8 vf = *(const short8*)&lV[cur][(nf * 16 + r) * 64 + ((kk * 4 + kq) ^ r7) * 8];
          O[nf] = __builtin_amdgcn_mfma_f32_16x16x32_bf16(pa, vf, O[nf], 0, 0, 0);
        }
      }
      asm volatile("s_waitcnt lgkmcnt(0)" ::: "memory");
      block_barrier();  // all reads done before next stage overwrites
    }

    // finalize: out[q][h*128+d] = O / l
    float inv[4];
#pragma unroll
    for (int i = 0; i < 4; ++i) inv[i] = 1.f / l_run[i];
#pragma unroll
    for (int nf = 0; nf < 8; ++nf)
#pragma unroll
      for (int i = 0; i < 4; ++i) {
        int qg = q0 + wrow + kq * 4 + i;
        out[(size_t)(b * 2048 + qg) * 2048 + h * 128 + nf * 16 + r] = f2bf(O[nf][i] * inv[i]);
      }
  }
}

extern "C" void kernel_launch(void* const* d_in, const int* in_sizes, int n_in,
                              void* d_out, int out_size, void* d_ws, size_t ws_size,
                              hipStream_t stream) {
  const float* x      = (const float*)d_in[0];
  const float* W_attn = (const float*)d_in[1];
  const float* b_attn = (const float*)d_in[2];
  const float* W_proj = (const float*)d_in[3];
  const float* b_proj = (const float*)d_in[4];
  float* y = (float*)d_out;

  // workspace carve-up (bf16 buffers), total 160 MB
  u16* xb     = (u16*)d_ws;                      // [4096][2048]
  u16* wqkvT  = xb     + (size_t)4096 * 2048;    // [6144][2048]
  u16* wprojT = wqkvT  + (size_t)6144 * 2048;    // [2048][2048]
  u16* qkv    = wprojT + (size_t)2048 * 2048;    // [4096][6144]
  u16* qh     = qkv    + (size_t)4096 * 6144;    // [32][2048][128]
  u16* kh     = qh     + (size_t)4096 * 2048;
  u16* vt     = kh     + (size_t)4096 * 2048;    // [32][128][2048]
  u16* attout = vt     + (size_t)4096 * 2048;    // [4096][2048]
  if (ws_size < (size_t)83886080 * 2) return;    // need 160 MB

  k_conv<<<8192, 256, 0, stream>>>(x, xb, 2097152);
  k_tconv<<<dim3(192, 64), dim3(32, 8), 0, stream>>>(W_attn, wqkvT, 2048, 6144);
  k_tconv<<<dim3(64, 64), dim3(32, 8), 0, stream>>>(W_proj, wprojT, 2048, 2048);
  k_gemm2<true><<<dim3(32, 24), 512, 0, stream>>>(xb, wqkvT, b_attn, qkv, 4096, 6144, 2048);
  k_rope<<<dim3(4096, 4), 256, 0, stream>>>(qkv, qh, kh);
  k_vtrans<<<dim3(64, 4, 32), dim3(32, 8), 0, stream>>>(qkv, vt);
  k_attn<<<dim3(16, 16, 2), 256, 0, stream>>>(qh, kh, vt, attout);
  k_gemm2<false><<<dim3(32, 8), 512, 0, stream>>>(attout, wprojT, b_proj, y, 4096, 2048, 2048);
}